// Round 15
// baseline (112.967 us; speedup 1.0000x reference)
//
#include <hip/hip_runtime.h>
#include <hip/hip_bf16.h>
#include <stdint.h>

#define B_ 8
#define C_ 512
#define N_ 2048

typedef __bf16 bf16_t;
typedef bf16_t bf16x8 __attribute__((ext_vector_type(8)));
typedef bf16_t bf16x4 __attribute__((ext_vector_type(4)));
typedef float f32x4 __attribute__((ext_vector_type(4)));

// ---------------------------------------------------------------------------
// prep (2241 blocks): k/v cast + row sums, weights. (q-transpose moved into
// the dkv dispatch — it has no dependency on kc/vc and its traffic overlaps
// the D-GEMM there instead of occupying a serial window.)
//   0..2047     k/v cast: 4 rows per block, batched loads (r14-proven)
//   2048..2240  weights: 0..63 WqT, 64..127 WkT, 128..191 Wv cast, 192 s1
// ---------------------------------------------------------------------------
__global__ __launch_bounds__(256) void prep_kernel(
    const float* __restrict__ kin, const float* __restrict__ vin,
    const float* __restrict__ wq, const float* __restrict__ wk,
    const float* __restrict__ wv, const float* __restrict__ bq,
    const float* __restrict__ bk,
    bf16_t* __restrict__ kc, bf16_t* __restrict__ vc,
    bf16_t* __restrict__ WqT, bf16_t* __restrict__ WkT, bf16_t* __restrict__ Wvb,
    float* __restrict__ s1p, float* __restrict__ sk, float* __restrict__ sv)
{
    __shared__ bf16_t tileA[64][65];
    __shared__ float red256[256];
    __shared__ float redr[4][4];
    const int bid = blockIdx.x;
    const int tid = threadIdx.x;

    if (bid < 2048) {
        // ---- k/v cast: 4 rows per block, batched loads ----
        const int r = bid;
        const int selv = r >> 10;
        const int row0 = (r & 1023) * 4;
        const float* src = (selv ? vin : kin) + (size_t)row0 * N_;
        bf16_t* dst = (selv ? vc : kc) + (size_t)row0 * N_;
        const int i = tid * 8;
        float4 f[4][2];
#pragma unroll
        for (int rr = 0; rr < 4; ++rr) {
            f[rr][0] = *(const float4*)(src + (size_t)rr * N_ + i);
            f[rr][1] = *(const float4*)(src + (size_t)rr * N_ + i + 4);
        }
        const int lane = tid & 63, wave = tid >> 6;
#pragma unroll
        for (int rr = 0; rr < 4; ++rr) {
            bf16x8 o;
            o[0] = (bf16_t)f[rr][0].x; o[1] = (bf16_t)f[rr][0].y;
            o[2] = (bf16_t)f[rr][0].z; o[3] = (bf16_t)f[rr][0].w;
            o[4] = (bf16_t)f[rr][1].x; o[5] = (bf16_t)f[rr][1].y;
            o[6] = (bf16_t)f[rr][1].z; o[7] = (bf16_t)f[rr][1].w;
            *(bf16x8*)(dst + (size_t)rr * N_ + i) = o;
            float s = f[rr][0].x + f[rr][0].y + f[rr][0].z + f[rr][0].w +
                      f[rr][1].x + f[rr][1].y + f[rr][1].z + f[rr][1].w;
#pragma unroll
            for (int d = 1; d < 64; d <<= 1) s += __shfl_xor(s, d, 64);
            if (lane == 0) redr[wave][rr] = s;
        }
        __syncthreads();
        if (tid < 4)
            (selv ? sv : sk)[row0 + tid] =
                redr[0][tid] + redr[1][tid] + redr[2][tid] + redr[3][tid];
    } else {
        // ---- weights roles (r11-proven) ----
        const int t = bid - 2048;
        if (t < 128) {
            const float* src = (t < 64) ? wq : wk;
            bf16_t* dst = (t < 64) ? WqT : WkT;
            const int j = t & 63;
            const int i0 = (j & 7) * 64, c0 = (j >> 3) * 64;
            const int cx = (tid & 15) * 4, ry = tid >> 4;
#pragma unroll
            for (int r = ry; r < 64; r += 16) {
                float4 f = *(const float4*)&src[(size_t)(c0 + r) * C_ + i0 + cx];
                tileA[r][cx + 0] = (bf16_t)f.x; tileA[r][cx + 1] = (bf16_t)f.y;
                tileA[r][cx + 2] = (bf16_t)f.z; tileA[r][cx + 3] = (bf16_t)f.w;
            }
            __syncthreads();
#pragma unroll
            for (int r = ry; r < 64; r += 16) {
                bf16x4 o;
                o[0] = tileA[cx + 0][r]; o[1] = tileA[cx + 1][r];
                o[2] = tileA[cx + 2][r]; o[3] = tileA[cx + 3][r];
                *(bf16x4*)&dst[(size_t)(i0 + r) * C_ + c0 + cx] = o;
            }
        } else if (t < 192) {
            const int j = t - 128;
#pragma unroll
            for (int p = 0; p < 4; ++p) {
                const int i = j * 4096 + p * 1024 + tid * 4;
                float4 f = *(const float4*)(wv + i);
                bf16x4 o;
                o[0] = (bf16_t)f.x; o[1] = (bf16_t)f.y;
                o[2] = (bf16_t)f.z; o[3] = (bf16_t)f.w;
                *(bf16x4*)(Wvb + i) = o;
            }
        } else {
            float p = bk[tid] * bq[tid] + bk[tid + 256] * bq[tid + 256];
            red256[tid] = p;
            __syncthreads();
            for (int s = 128; s > 0; s >>= 1) {
                if (tid < s) red256[tid] += red256[tid + s];
                __syncthreads();
            }
            if (tid == 0) s1p[0] = red256[0];
        }
    }
}

// ---------------------------------------------------------------------------
// dkv_M_q (2640 blocks, one dispatch):
//   0..511      Dp[b*4+sp][i,j] = sum_{n in sp} kc[i,n]*vc[j,n] (128-tile)
//   512..2559   q transpose-cast -> qT (no dep on kc/vc; overlaps the GEMM)
//   2560..2623  M[i',i] = sum_c WqT[i',c]*WkT[i,c]  (64-tile)
//   2624..2639  gk = WkT.bq, va = WqT.bk
// LDS: As/Bs 32 KB; transpose tile carved from As (8.3 KB <= 16 KB).
// ---------------------------------------------------------------------------
__global__ __launch_bounds__(256, 2) void dkv_M_q_kernel(
    const bf16_t* __restrict__ kc, const bf16_t* __restrict__ vc,
    bf16_t* __restrict__ Dp, const float* __restrict__ q,
    bf16_t* __restrict__ qT,
    const bf16_t* __restrict__ WqT, const bf16_t* __restrict__ WkT,
    bf16_t* __restrict__ M, const float* __restrict__ bq,
    const float* __restrict__ bk, float* __restrict__ gk,
    float* __restrict__ va)
{
    __shared__ __align__(16) bf16_t As[128 * 64];
    __shared__ __align__(16) bf16_t Bs[128 * 64];
    const int f = blockIdx.x;
    const int tid = threadIdx.x, lane = tid & 63, wave = tid >> 6;
    const int wr = wave >> 1, wc = wave & 1;
    const size_t sCC = (size_t)C_ * C_;
    const size_t sBN = (size_t)N_ * C_;

    if (f < 512) {
        const int zz = f >> 4;
        const int bz = zz >> 2, sp = zz & 3;
        const int t4 = f & 15;
        const int m0 = (t4 >> 2) * 128, n0 = (t4 & 3) * 128;
        const int kbeg = sp * 512;
        const bf16_t* Ab = kc + (size_t)bz * sBN;
        const bf16_t* Bb = vc + (size_t)bz * sBN;

        f32x4 acc[4][4];
#pragma unroll
        for (int i = 0; i < 4; ++i)
#pragma unroll
            for (int j = 0; j < 4; ++j) acc[i][j] = 0.f;

        const int srow = tid >> 3;
        const int scol = ((tid & 7) ^ (srow & 7)) * 8;
        const int ldso = tid * 16;

        for (int t = 0; t < 8; ++t) {
            const bf16_t* ga = Ab + (size_t)(m0 + srow) * N_ + kbeg + t * 64 + scol;
            const bf16_t* gb = Bb + (size_t)(n0 + srow) * N_ + kbeg + t * 64 + scol;
#pragma unroll
            for (int p = 0; p < 4; ++p)
                __builtin_amdgcn_global_load_lds(
                    (const __attribute__((address_space(1))) void*)(ga + (size_t)p * 32 * N_),
                    (__attribute__((address_space(3))) void*)((char*)As + ldso + p * 4096),
                    16, 0, 0);
#pragma unroll
            for (int p = 0; p < 4; ++p)
                __builtin_amdgcn_global_load_lds(
                    (const __attribute__((address_space(1))) void*)(gb + (size_t)p * 32 * N_),
                    (__attribute__((address_space(3))) void*)((char*)Bs + ldso + p * 4096),
                    16, 0, 0);
            __syncthreads();

#pragma unroll
            for (int kk = 0; kk < 64; kk += 32) {
                bf16x8 af[4], bfr[4];
                const int kcol = kk + (lane >> 4) * 8;
                const int kcn = kcol >> 3;
#pragma unroll
                for (int m = 0; m < 4; ++m) {
                    const int r = wr * 64 + (lane & 15) + m * 16;
                    af[m] = *(const bf16x8*)((const char*)As + r * 128 +
                                             ((kcn ^ (r & 7)) << 4));
                }
#pragma unroll
                for (int n = 0; n < 4; ++n) {
                    const int r = wc * 64 + (lane & 15) + n * 16;
                    bfr[n] = *(const bf16x8*)((const char*)Bs + r * 128 +
                                              ((kcn ^ (r & 7)) << 4));
                }
#pragma unroll
                for (int m = 0; m < 4; ++m)
#pragma unroll
                    for (int n = 0; n < 4; ++n)
                        acc[m][n] = __builtin_amdgcn_mfma_f32_16x16x32_bf16(
                            af[m], bfr[n], acc[m][n], 0, 0, 0);
            }
            __syncthreads();
        }

        const int rj = (lane >> 4) * 4;
        const int cc = lane & 15;
#pragma unroll
        for (int m = 0; m < 4; ++m)
#pragma unroll
            for (int n = 0; n < 4; ++n) {
                const int col = n0 + wc * 64 + n * 16 + cc;
                f32x4 vv = acc[m][n];
#pragma unroll
                for (int j = 0; j < 4; ++j) {
                    const int row = m0 + wr * 64 + m * 16 + rj + j;
                    Dp[(size_t)zz * sCC + (size_t)row * C_ + col] = (bf16_t)vv[j];
                }
            }
    } else if (f < 2560) {
        // ---- q transpose (r13-proven body; tile carved from As) ----
        bf16_t (*tile)[65] = (bf16_t(*)[65])As;
        const int t = f - 512;
        const int b = t >> 8;
        const int rem = t & 255;
        const int c0 = (rem >> 5) * 64;
        const int n0 = (rem & 31) * 64;
        const float* src = q + (size_t)b * C_ * N_;
        bf16_t* dT = qT + (size_t)b * N_ * C_;
        const int cx = (tid & 15) * 4, ry = tid >> 4;
#pragma unroll
        for (int r = ry; r < 64; r += 16) {
            float4 ff = *(const float4*)&src[(size_t)(c0 + r) * N_ + n0 + cx];
            tile[r][cx + 0] = (bf16_t)ff.x; tile[r][cx + 1] = (bf16_t)ff.y;
            tile[r][cx + 2] = (bf16_t)ff.z; tile[r][cx + 3] = (bf16_t)ff.w;
        }
        __syncthreads();
#pragma unroll
        for (int r = ry; r < 64; r += 16) {
            bf16x4 o;
            o[0] = tile[cx + 0][r]; o[1] = tile[cx + 1][r];
            o[2] = tile[cx + 2][r]; o[3] = tile[cx + 3][r];
            *(bf16x4*)&dT[(size_t)(n0 + r) * C_ + c0 + cx] = o;
        }
    } else if (f < 2624) {
        const int g = f - 2560;
        const int m0 = (g >> 3) * 64, n0 = (g & 7) * 64;
        f32x4 acc[2][2];
#pragma unroll
        for (int i = 0; i < 2; ++i)
#pragma unroll
            for (int j = 0; j < 2; ++j) acc[i][j] = 0.f;
        const int srow = tid >> 3;
        const int scol = ((tid & 7) ^ (srow & 7)) * 8;
        const int ldso = tid * 16;
        for (int t = 0; t < 8; ++t) {
            const bf16_t* ga = WqT + (size_t)(m0 + srow) * C_ + t * 64 + scol;
            const bf16_t* gb = WkT + (size_t)(n0 + srow) * C_ + t * 64 + scol;
#pragma unroll
            for (int p = 0; p < 2; ++p)
                __builtin_amdgcn_global_load_lds(
                    (const __attribute__((address_space(1))) void*)(ga + (size_t)p * 32 * C_),
                    (__attribute__((address_space(3))) void*)((char*)As + ldso + p * 4096),
                    16, 0, 0);
#pragma unroll
            for (int p = 0; p < 2; ++p)
                __builtin_amdgcn_global_load_lds(
                    (const __attribute__((address_space(1))) void*)(gb + (size_t)p * 32 * C_),
                    (__attribute__((address_space(3))) void*)((char*)Bs + ldso + p * 4096),
                    16, 0, 0);
            __syncthreads();
#pragma unroll
            for (int kk = 0; kk < 64; kk += 32) {
                bf16x8 af[2], bfr[2];
                const int kcol = kk + (lane >> 4) * 8;
                const int kcn = kcol >> 3;
#pragma unroll
                for (int m = 0; m < 2; ++m) {
                    const int r = wr * 32 + (lane & 15) + m * 16;
                    af[m] = *(const bf16x8*)((const char*)As + r * 128 +
                                             ((kcn ^ (r & 7)) << 4));
                }
#pragma unroll
                for (int n = 0; n < 2; ++n) {
                    const int r = wc * 32 + (lane & 15) + n * 16;
                    bfr[n] = *(const bf16x8*)((const char*)Bs + r * 128 +
                                              ((kcn ^ (r & 7)) << 4));
                }
#pragma unroll
                for (int m = 0; m < 2; ++m)
#pragma unroll
                    for (int n = 0; n < 2; ++n)
                        acc[m][n] = __builtin_amdgcn_mfma_f32_16x16x32_bf16(
                            af[m], bfr[n], acc[m][n], 0, 0, 0);
            }
            __syncthreads();
        }
        const int rj = (lane >> 4) * 4;
        const int cc = lane & 15;
#pragma unroll
        for (int m = 0; m < 2; ++m)
#pragma unroll
            for (int n = 0; n < 2; ++n) {
                const int col = n0 + wc * 32 + n * 16 + cc;
                f32x4 vv = acc[m][n];
#pragma unroll
                for (int j = 0; j < 4; ++j) {
                    const int row = m0 + wr * 32 + m * 16 + rj + j;
                    M[(size_t)row * C_ + col] = (bf16_t)vv[j];
                }
            }
    } else {
        const int j = f - 2624;
        const bf16_t* W = (j < 8) ? WkT : WqT;
        const float* bb = (j < 8) ? bq : bk;
        float* out = (j < 8) ? gk : va;
        const int row = (j & 7) * 64 + (tid >> 2);
        const int c0 = (tid & 3) * 128;
        const bf16_t* rp = W + (size_t)row * C_ + c0;
        float acc = 0.f;
#pragma unroll
        for (int e = 0; e < 128; e += 8) {
            bf16x8 vv = *(const bf16x8*)(rp + e);
#pragma unroll
            for (int x = 0; x < 8; ++x) acc += (float)vv[x] * bb[c0 + e + x];
        }
        acc += __shfl_xor(acc, 1, 64);
        acc += __shfl_xor(acc, 2, 64);
        if ((tid & 3) == 0) out[row] = acc;
    }
}

// ---------------------------------------------------------------------------
// p1_fused (528 blocks):
//   0..511   P1[bz][c2,i] = sum_{sp,j} Wv[c2,j] * Dp[bz*4+sp][i,j]
//   512..519 u[b] = Wv . sv[b]
//   520..527 vbraw[b] = M . sk[b];  s2[b] = sk[b].gk + N*s1
// ---------------------------------------------------------------------------
__global__ __launch_bounds__(256) void p1_fused_kernel(
    const bf16_t* __restrict__ Wvb, const bf16_t* __restrict__ Dp,
    bf16_t* __restrict__ P1, const bf16_t* __restrict__ M,
    const float* __restrict__ sk, const float* __restrict__ sv,
    const float* __restrict__ gk, const float* __restrict__ s1p,
    float* __restrict__ u, float* __restrict__ vbraw, float* __restrict__ s2)
{
    __shared__ __align__(16) bf16_t As[64 * 64];
    __shared__ __align__(16) bf16_t Bs[64 * 64];
    __shared__ float svec[C_];
    __shared__ float red[256];
    const int f = blockIdx.x;
    const int tid = threadIdx.x, lane = tid & 63, wave = tid >> 6;
    const int wr = wave >> 1, wc = wave & 1;
    const size_t sCC = (size_t)C_ * C_;

    if (f < 512) {
        const int bz = f >> 6;
        const int m0 = ((f >> 3) & 7) * 64, n0 = (f & 7) * 64;
        f32x4 acc[2][2];
#pragma unroll
        for (int i = 0; i < 2; ++i)
#pragma unroll
            for (int j = 0; j < 2; ++j) acc[i][j] = 0.f;
        const int srow = tid >> 3;
        const int scol = ((tid & 7) ^ (srow & 7)) * 8;
        const int ldso = tid * 16;

        for (int sp = 0; sp < 4; ++sp) {
            const bf16_t* Bb = Dp + (size_t)(bz * 4 + sp) * sCC;
            for (int t = 0; t < 8; ++t) {
                const bf16_t* ga = Wvb + (size_t)(m0 + srow) * C_ + t * 64 + scol;
                const bf16_t* gb = Bb + (size_t)(n0 + srow) * C_ + t * 64 + scol;
#pragma unroll
                for (int p = 0; p < 2; ++p)
                    __builtin_amdgcn_global_load_lds(
                        (const __attribute__((address_space(1))) void*)(ga + (size_t)p * 32 * C_),
                        (__attribute__((address_space(3))) void*)((char*)As + ldso + p * 4096),
                        16, 0, 0);
#pragma unroll
                for (int p = 0; p < 2; ++p)
                    __builtin_amdgcn_global_load_lds(
                        (const __attribute__((address_space(1))) void*)(gb + (size_t)p * 32 * C_),
                        (__attribute__((address_space(3))) void*)((char*)Bs + ldso + p * 4096),
                        16, 0, 0);
                __syncthreads();
#pragma unroll
                for (int kk = 0; kk < 64; kk += 32) {
                    bf16x8 af[2], bfr[2];
                    const int kcol = kk + (lane >> 4) * 8;
                    const int kcn = kcol >> 3;
#pragma unroll
                    for (int m = 0; m < 2; ++m) {
                        const int r = wr * 32 + (lane & 15) + m * 16;
                        af[m] = *(const bf16x8*)((const char*)As + r * 128 +
                                                 ((kcn ^ (r & 7)) << 4));
                    }
#pragma unroll
                    for (int n = 0; n < 2; ++n) {
                        const int r = wc * 32 + (lane & 15) + n * 16;
                        bfr[n] = *(const bf16x8*)((const char*)Bs + r * 128 +
                                                  ((kcn ^ (r & 7)) << 4));
                    }
#pragma unroll
                    for (int m = 0; m < 2; ++m)
#pragma unroll
                        for (int n = 0; n < 2; ++n)
                            acc[m][n] = __builtin_amdgcn_mfma_f32_16x16x32_bf16(
                                af[m], bfr[n], acc[m][n], 0, 0, 0);
                }
                __syncthreads();
            }
        }
        const int rj = (lane >> 4) * 4;
        const int cc = lane & 15;
#pragma unroll
        for (int m = 0; m < 2; ++m)
#pragma unroll
            for (int n = 0; n < 2; ++n) {
                const int col = n0 + wc * 32 + n * 16 + cc;
                f32x4 vv = acc[m][n];
#pragma unroll
                for (int j = 0; j < 4; ++j) {
                    const int row = m0 + wr * 32 + m * 16 + rj + j;
                    P1[(size_t)bz * sCC + (size_t)row * C_ + col] = (bf16_t)vv[j];
                }
            }
    } else if (f < 520) {
        const int b = f - 512;
        const float* s4 = sv + (size_t)b * C_;
        svec[tid * 2] = s4[tid * 2];
        svec[tid * 2 + 1] = s4[tid * 2 + 1];
        __syncthreads();
        const int c = tid * 2;
#pragma unroll
        for (int rr = 0; rr < 2; ++rr) {
            const bf16_t* row = Wvb + (size_t)(c + rr) * C_;
            float acc = 0.f;
            for (int j = 0; j < C_; j += 8) {
                bf16x8 vv = *(const bf16x8*)(row + j);
#pragma unroll
                for (int e = 0; e < 8; ++e) acc += (float)vv[e] * svec[j + e];
            }
            u[b * C_ + c + rr] = acc;
        }
    } else {
        const int b = f - 520;
        const float* s4 = sk + (size_t)b * C_;
        svec[tid * 2] = s4[tid * 2];
        svec[tid * 2 + 1] = s4[tid * 2 + 1];
        __syncthreads();
        const int c = tid * 2;
#pragma unroll
        for (int rr = 0; rr < 2; ++rr) {
            const bf16_t* row = M + (size_t)(c + rr) * C_;
            float acc = 0.f;
            for (int j = 0; j < C_; j += 8) {
                bf16x8 vv = *(const bf16x8*)(row + j);
#pragma unroll
                for (int e = 0; e < 8; ++e) acc += (float)vv[e] * svec[j + e];
            }
            vbraw[b * C_ + c + rr] = acc;
        }
        float p = svec[tid] * gk[tid] + svec[tid + 256] * gk[tid + 256];
        red[tid] = p;
        __syncthreads();
        for (int s = 128; s > 0; s >>= 1) {
            if (tid < s) red[tid] += red[tid + s];
            __syncthreads();
        }
        if (tid == 0) s2[b] = red[0] + 2048.0f * s1p[0];
    }
}

// ---------------------------------------------------------------------------
// HT GEMM (64-tile, K=512): HT = P1.M^T + u (x) va + bv (x) (vbraw + N*va);
// x==0 blocks also compute h (r11-verified fold).
// ---------------------------------------------------------------------------
__global__ __launch_bounds__(256) void gemm_ht(
    const bf16_t* __restrict__ A, const bf16_t* __restrict__ Bm,
    bf16_t* __restrict__ Cout,
    const float* __restrict__ e0, const float* __restrict__ e1,
    const float* __restrict__ e2, const float* __restrict__ e3,
    const float* __restrict__ bqv, float* __restrict__ hout,
    const float* __restrict__ s1p, const float* __restrict__ s2p)
{
    __shared__ __align__(16) bf16_t As[64 * 64];
    __shared__ __align__(16) bf16_t Bs[64 * 64];

    const int tid = threadIdx.x, lane = tid & 63, wave = tid >> 6;
    const int wr = wave >> 1, wc = wave & 1;
    const int bz = blockIdx.z;
    const int m0 = blockIdx.y * 64, n0 = blockIdx.x * 64;
    const size_t sCC = (size_t)C_ * C_;

    const bf16_t* Ab = A + (size_t)bz * sCC;

    f32x4 acc[2][2];
#pragma unroll
    for (int i = 0; i < 2; ++i)
#pragma unroll
        for (int j = 0; j < 2; ++j) acc[i][j] = 0.f;

    const int srow = tid >> 3;
    const int scol = ((tid & 7) ^ (srow & 7)) * 8;
    const int ldso = tid * 16;

    float hacc = 0.f;
    const bool doH = (blockIdx.x == 0);

    for (int t = 0; t < 8; ++t) {
        const bf16_t* ga = Ab + (size_t)(m0 + srow) * C_ + t * 64 + scol;
        const bf16_t* gb = Bm + (size_t)(n0 + srow) * C_ + t * 64 + scol;
#pragma unroll
        for (int p = 0; p < 2; ++p)
            __builtin_amdgcn_global_load_lds(
                (const __attribute__((address_space(1))) void*)(ga + (size_t)p * 32 * C_),
                (__attribute__((address_space(3))) void*)((char*)As + ldso + p * 4096),
                16, 0, 0);
#pragma unroll
        for (int p = 0; p < 2; ++p)
            __builtin_amdgcn_global_load_lds(
                (const __attribute__((address_space(1))) void*)(gb + (size_t)p * 32 * C_),
                (__attribute__((address_space(3))) void*)((char*)Bs + ldso + p * 4096),
                16, 0, 0);
        __syncthreads();

#pragma unroll
        for (int kk = 0; kk < 64; kk += 32) {
            bf16x8 af[2], bfr[2];
            const int kcol = kk + (lane >> 4) * 8;
            const int kcn = kcol >> 3;
#pragma unroll
            for (int m = 0; m < 2; ++m) {
                const int r = wr * 32 + (lane & 15) + m * 16;
                af[m] = *(const bf16x8*)((const char*)As + r * 128 +
                                         ((kcn ^ (r & 7)) << 4));
            }
#pragma unroll
            for (int n = 0; n < 2; ++n) {
                const int r = wc * 32 + (lane & 15) + n * 16;
                bfr[n] = *(const bf16x8*)((const char*)Bs + r * 128 +
                                          ((kcn ^ (r & 7)) << 4));
            }
#pragma unroll
            for (int m = 0; m < 2; ++m)
#pragma unroll
                for (int n = 0; n < 2; ++n)
                    acc[m][n] = __builtin_amdgcn_mfma_f32_16x16x32_bf16(
                        af[m], bfr[n], acc[m][n], 0, 0, 0);
        }
        if (doH) {
            const int rr = tid >> 2, qq = tid & 3;
#pragma unroll
            for (int uq = 0; uq < 2; ++uq) {
                const int c = qq * 2 + uq;
                bf16x8 av = *(const bf16x8*)((const char*)As + rr * 128 +
                                             ((c ^ (rr & 7)) << 4));
                const float* bp = bqv + t * 64 + c * 8;
#pragma unroll
                for (int e = 0; e < 8; ++e) hacc += (float)av[e] * bp[e];
            }
        }
        __syncthreads();
    }

    const int rj = (lane >> 4) * 4;
    const int cc = lane & 15;
#pragma unroll
    for (int m = 0; m < 2; ++m) {
#pragma unroll
        for (int n = 0; n < 2; ++n) {
            const int col = n0 + wc * 32 + n * 16 + cc;
            f32x4 vv = acc[m][n];
#pragma unroll
            for (int j = 0; j < 4; ++j) {
                const int row = m0 + wr * 32 + m * 16 + rj + j;
                float val = vv[j] + e0[bz * C_ + row] * e1[col] +
                            e2[row] * (e3[bz * C_ + col] + 2048.0f * e1[col]);
                Cout[(size_t)bz * sCC + (size_t)row * C_ + col] = (bf16_t)val;
            }
        }
    }
    if (doH) {
        hacc += __shfl_xor(hacc, 1, 64);
        hacc += __shfl_xor(hacc, 2, 64);
        if ((tid & 3) == 0) {
            const int row = m0 + (tid >> 2);
            hout[bz * C_ + row] = hacc + e0[bz * C_ + row] * s1p[0] +
                                  e2[row] * s2p[bz];
        }
    }
}

// ---------------------------------------------------------------------------
// Final GEMM: out[c,n] = sum_i HT[c,i]*qT[n,i] + h[b][c] + q[c,n] (fp32 resid).
// 1-D XCD-swizzled grid (512).
// ---------------------------------------------------------------------------
__global__ __launch_bounds__(256) void gemm_final(
    const bf16_t* __restrict__ A, const bf16_t* __restrict__ Bm,
    float* __restrict__ Cout, const float* __restrict__ qres,
    const float* __restrict__ hvec)
{
    __shared__ __align__(16) bf16_t As[128 * 64];
    __shared__ __align__(16) bf16_t Bs[128 * 64];

    const int f = blockIdx.x;
    const int xcd = f & 7, sl = f >> 3;
    const int g = xcd + 8 * (sl >> 2);
    const int m0 = (sl & 3) * 128;
    const int bz = g >> 4;
    const int n0 = (g & 15) * 128;
    const int K = C_;

    const int tid = threadIdx.x, lane = tid & 63, wave = tid >> 6;
    const int wr = wave >> 1, wc = wave & 1;

    const bf16_t* Ab = A + (size_t)bz * ((size_t)C_ * C_);
    const bf16_t* Bb = Bm + (size_t)bz * ((size_t)N_ * C_);

    f32x4 acc[4][4];
#pragma unroll
    for (int i = 0; i < 4; ++i)
#pragma unroll
        for (int j = 0; j < 4; ++j) acc[i][j] = 0.f;

    const int srow = tid >> 3;
    const int scol = ((tid & 7) ^ (srow & 7)) * 8;
    const int ldso = tid * 16;

    for (int t = 0; t < 8; ++t) {
        const bf16_t* ga = Ab + (size_t)(m0 + srow) * K + t * 64 + scol;
        const bf16_t* gb = Bb + (size_t)(n0 + srow) * K + t * 64 + scol;
#pragma unroll
        for (int p = 0; p < 4; ++p)
            __builtin_amdgcn_global_load_lds(
                (const __attribute__((address_space(1))) void*)(ga + (size_t)p * 32 * K),
                (__attribute__((address_space(3))) void*)((char*)As + ldso + p * 4096),
                16, 0, 0);
#pragma unroll
        for (int p = 0; p < 4; ++p)
            __builtin_amdgcn_global_load_lds(
                (const __attribute__((address_space(1))) void*)(gb + (size_t)p * 32 * K),
                (__attribute__((address_space(3))) void*)((char*)Bs + ldso + p * 4096),
                16, 0, 0);
        __syncthreads();

#pragma unroll
        for (int kk = 0; kk < 64; kk += 32) {
            bf16x8 af[4], bfr[4];
            const int kcol = kk + (lane >> 4) * 8;
            const int kcn = kcol >> 3;
#pragma unroll
            for (int m = 0; m < 4; ++m) {
                const int r = wr * 64 + (lane & 15) + m * 16;
                af[m] = *(const bf16x8*)((const char*)As + r * 128 +
                                         ((kcn ^ (r & 7)) << 4));
            }
#pragma unroll
            for (int n = 0; n < 4; ++n) {
                const int r = wc * 64 + (lane & 15) + n * 16;
                bfr[n] = *(const bf16x8*)((const char*)Bs + r * 128 +
                                          ((kcn ^ (r & 7)) << 4));
            }
#pragma unroll
            for (int m = 0; m < 4; ++m)
#pragma unroll
                for (int n = 0; n < 4; ++n)
                    acc[m][n] = __builtin_amdgcn_mfma_f32_16x16x32_bf16(
                        af[m], bfr[n], acc[m][n], 0, 0, 0);
        }
        __syncthreads();
    }

    const int rj = (lane >> 4) * 4;
    const int cc = lane & 15;
    const size_t ob = (size_t)bz * ((size_t)C_ * N_);
#pragma unroll
    for (int m = 0; m < 4; ++m) {
#pragma unroll
        for (int n = 0; n < 4; ++n) {
            const int col = n0 + wc * 64 + n * 16 + cc;
            f32x4 vv = acc[m][n];
#pragma unroll
            for (int j = 0; j < 4; ++j) {
                const int row = m0 + wr * 64 + m * 16 + rj + j;
                const size_t o = ob + (size_t)row * N_ + col;
                Cout[o] = vv[j] + hvec[bz * C_ + row] + qres[o];
            }
        }
    }
}

// ---------------------------------------------------------------------------
extern "C" void kernel_launch(void* const* d_in, const int* in_sizes, int n_in,
                              void* d_out, int out_size, void* d_ws, size_t ws_size,
                              hipStream_t stream)
{
    (void)in_sizes; (void)n_in; (void)out_size; (void)ws_size;
    const float* q  = (const float*)d_in[0];
    const float* k  = (const float*)d_in[1];
    const float* v  = (const float*)d_in[2];
    const float* wq = (const float*)d_in[3];
    const float* bq = (const float*)d_in[4];
    const float* wk = (const float*)d_in[5];
    const float* bk = (const float*)d_in[6];
    const float* wv = (const float*)d_in[7];
    const float* bv = (const float*)d_in[8];
    float* out = (float*)d_out;

    char* ws = (char*)d_ws;
    const size_t WSZ = (size_t)C_ * C_ * 2;            // 512 KB
    const size_t TSZ = (size_t)B_ * N_ * C_ * 2;       // 16.78 MB
    const size_t SCZ = (size_t)B_ * C_ * C_ * 2;       // 4.19 MB
    const size_t VSZ = (size_t)B_ * C_ * 4;            // 16 KB
    size_t off = 0;
    bf16_t* WqTb = (bf16_t*)(ws + off); off += WSZ;
    bf16_t* WkTb = (bf16_t*)(ws + off); off += WSZ;
    bf16_t* Wvb  = (bf16_t*)(ws + off); off += WSZ;
    bf16_t* M    = (bf16_t*)(ws + off); off += WSZ;
    bf16_t* qT   = (bf16_t*)(ws + off); off += TSZ;
    bf16_t* kc   = (bf16_t*)(ws + off); off += TSZ;
    bf16_t* vc   = (bf16_t*)(ws + off); off += TSZ;
    bf16_t* Dp   = (bf16_t*)(ws + off); off += TSZ;    // 32 x sCC partials
    bf16_t* P1   = (bf16_t*)(ws + off); off += SCZ;
    bf16_t* HT   = (bf16_t*)(ws + off); off += SCZ;
    float*  sk   = (float*)(ws + off);  off += VSZ;
    float*  sv   = (float*)(ws + off);  off += VSZ;
    float*  gk   = (float*)(ws + off);  off += C_ * 4;
    float*  va   = (float*)(ws + off);  off += C_ * 4;
    float*  s1p  = (float*)(ws + off);  off += 64;
    float*  s2   = (float*)(ws + off);  off += 64;
    float*  uu   = (float*)(ws + off);  off += VSZ;
    float*  vbr  = (float*)(ws + off);  off += VSZ;
    float*  hb   = (float*)(ws + off);  off += VSZ;

    const dim3 blk(256);

    // 1. prep: k/v cast + sums; weights (WqT/WkT/Wv/s1)
    prep_kernel<<<dim3(2241), blk, 0, stream>>>(
        k, v, wq, wk, wv, bq, bk, kc, vc, WqTb, WkTb, Wvb, s1p, sk, sv);

    // 2. Dp split-K GEMM + q-transpose (overlapped) + M + gk/va
    dkv_M_q_kernel<<<dim3(2640), blk, 0, stream>>>(
        kc, vc, Dp, q, qT, WqTb, WkTb, M, bq, bk, gk, va);

    // 3. P1 = Wv . (sum_sp Dp)^T (K=2048, reduce fused) + u/vbraw/s2
    p1_fused_kernel<<<dim3(528), blk, 0, stream>>>(
        Wvb, Dp, P1, M, sk, sv, gk, s1p, uu, vbr, s2);

    // 4. HT = P1.M^T + rank-1; h folded into x==0 blocks
    gemm_ht<<<dim3(8, 8, B_), blk, 0, stream>>>(
        P1, M, HT, uu, va, bv, vbr, gk, hb, s1p, s2);

    // 5. out = HT.qT^T + h + q  (fp32 residual read directly)
    gemm_final<<<dim3(512), blk, 0, stream>>>(HT, qT, out, q, hb);
}

// Round 16
// 102.443 us; speedup vs baseline: 1.1027x; 1.1027x over previous
//
#include <hip/hip_runtime.h>
#include <hip/hip_bf16.h>
#include <stdint.h>

#define B_ 8
#define C_ 512
#define N_ 2048

typedef __bf16 bf16_t;
typedef bf16_t bf16x8 __attribute__((ext_vector_type(8)));
typedef bf16_t bf16x4 __attribute__((ext_vector_type(4)));
typedef float f32x4 __attribute__((ext_vector_type(4)));

// ---------------------------------------------------------------------------
// prep_qw (2241 blocks): q transpose + weight transposes/cast + s1.
//   0..2047     qT[b][n][c] = (bf16)q[b][c][n]  (64x64 tiles, r13-proven)
//   2048..2175  WqT (0..63) / WkT (64..127) transpose-cast
//   2176..2239  Wv cast
//   2240        s1 = bk.bq
// NOTE: no k/v cast pass — the D-GEMM reads fp32 k,v directly (r9-proven).
// ---------------------------------------------------------------------------
__global__ __launch_bounds__(256) void prep_qw_kernel(
    const float* __restrict__ q,
    const float* __restrict__ wq, const float* __restrict__ wk,
    const float* __restrict__ wv, const float* __restrict__ bq,
    const float* __restrict__ bk,
    bf16_t* __restrict__ qT,
    bf16_t* __restrict__ WqT, bf16_t* __restrict__ WkT, bf16_t* __restrict__ Wvb,
    float* __restrict__ s1p)
{
    __shared__ bf16_t tile[64][65];
    __shared__ float red256[256];
    const int bid = blockIdx.x;
    const int tid = threadIdx.x;

    if (bid < 2048) {
        const int b = bid >> 8;
        const int rem = bid & 255;
        const int c0 = (rem >> 5) * 64;
        const int n0 = (rem & 31) * 64;
        const float* src = q + (size_t)b * C_ * N_;
        bf16_t* dT = qT + (size_t)b * N_ * C_;
        const int cx = (tid & 15) * 4, ry = tid >> 4;
#pragma unroll
        for (int r = ry; r < 64; r += 16) {
            float4 f = *(const float4*)&src[(size_t)(c0 + r) * N_ + n0 + cx];
            tile[r][cx + 0] = (bf16_t)f.x; tile[r][cx + 1] = (bf16_t)f.y;
            tile[r][cx + 2] = (bf16_t)f.z; tile[r][cx + 3] = (bf16_t)f.w;
        }
        __syncthreads();
#pragma unroll
        for (int r = ry; r < 64; r += 16) {
            bf16x4 o;
            o[0] = tile[cx + 0][r]; o[1] = tile[cx + 1][r];
            o[2] = tile[cx + 2][r]; o[3] = tile[cx + 3][r];
            *(bf16x4*)&dT[(size_t)(n0 + r) * C_ + c0 + cx] = o;
        }
    } else if (bid < 2176) {
        const int t = bid - 2048;
        const float* src = (t < 64) ? wq : wk;
        bf16_t* dst = (t < 64) ? WqT : WkT;
        const int j = t & 63;
        const int i0 = (j & 7) * 64, c0 = (j >> 3) * 64;
        const int cx = (tid & 15) * 4, ry = tid >> 4;
#pragma unroll
        for (int r = ry; r < 64; r += 16) {
            float4 f = *(const float4*)&src[(size_t)(c0 + r) * C_ + i0 + cx];
            tile[r][cx + 0] = (bf16_t)f.x; tile[r][cx + 1] = (bf16_t)f.y;
            tile[r][cx + 2] = (bf16_t)f.z; tile[r][cx + 3] = (bf16_t)f.w;
        }
        __syncthreads();
#pragma unroll
        for (int r = ry; r < 64; r += 16) {
            bf16x4 o;
            o[0] = tile[cx + 0][r]; o[1] = tile[cx + 1][r];
            o[2] = tile[cx + 2][r]; o[3] = tile[cx + 3][r];
            *(bf16x4*)&dst[(size_t)(i0 + r) * C_ + c0 + cx] = o;
        }
    } else if (bid < 2240) {
        const int j = bid - 2176;
#pragma unroll
        for (int p = 0; p < 4; ++p) {
            const int i = j * 4096 + p * 1024 + tid * 4;
            float4 f = *(const float4*)(wv + i);
            bf16x4 o;
            o[0] = (bf16_t)f.x; o[1] = (bf16_t)f.y;
            o[2] = (bf16_t)f.z; o[3] = (bf16_t)f.w;
            *(bf16x4*)(Wvb + i) = o;
        }
    } else {
        float p = bk[tid] * bq[tid] + bk[tid + 256] * bq[tid + 256];
        red256[tid] = p;
        __syncthreads();
        for (int s = 128; s > 0; s >>= 1) {
            if (tid < s) red256[tid] += red256[tid + s];
            __syncthreads();
        }
        if (tid == 0) s1p[0] = red256[0];
    }
}

// ---------------------------------------------------------------------------
// dkv_M (592 blocks): fp32-direct D-GEMM (r9-proven, 39.7us) + M + gk/va.
//   0..511   Dp[b*4+sp][i,j] = sum_{n in sp} k[b,i,n]*v[b,j,n]
//            fp32 k,v via global_load_lds, BK=64 (2x32 KB fp32 LDS),
//            chunk swizzle slot = c ^ (r&7), sk4/sv4 side sums by edge blocks.
//   512..575 M[i',i] = sum_c WqT[i',c]*WkT[i,c]  (64-tile bf16, LDS aliased)
//   576..591 gk = WkT.bq (8), va = WqT.bk (8)
// ---------------------------------------------------------------------------
__global__ __launch_bounds__(256) void dkv_M_kernel(
    const float* __restrict__ Kin, const float* __restrict__ Vin,
    bf16_t* __restrict__ Dp, float* __restrict__ sk4, float* __restrict__ sv4,
    const bf16_t* __restrict__ WqT, const bf16_t* __restrict__ WkT,
    bf16_t* __restrict__ M, const float* __restrict__ bq,
    const float* __restrict__ bk, float* __restrict__ gk,
    float* __restrict__ va)
{
    __shared__ __align__(16) float AsF[128 * 64];   // 32 KB
    __shared__ __align__(16) float BsF[128 * 64];   // 32 KB

    const int f = blockIdx.x;
    const int tid = threadIdx.x, lane = tid & 63, wave = tid >> 6;
    const int wr = wave >> 1, wc = wave & 1;
    const size_t sCC = (size_t)C_ * C_;

    if (f < 512) {
        const int xcd = f & 7, sl = f >> 3;
        const int g = xcd + 8 * (sl >> 4), t5 = sl & 15;   // g in [0,32)
        const int bz = g >> 2, sp = g & 3;
        const int m0 = (t5 >> 2) * 128, n0 = (t5 & 3) * 128;
        const int kbeg = sp * 512;

        const float* Ab = Kin + (size_t)bz * C_ * N_;
        const float* Bb = Vin + (size_t)bz * C_ * N_;

        f32x4 acc[4][4];
#pragma unroll
        for (int i = 0; i < 4; ++i)
#pragma unroll
            for (int j = 0; j < 4; ++j) acc[i][j] = 0.f;

        const int prow = tid >> 4;                      // 0..15
        const int cs   = (tid & 15) ^ (prow & 7);
        const int ldso = tid * 16;

        const int srr = tid >> 1, hh = tid & 1;
        float hsA = 0.f, hsB = 0.f;
        const bool doA = (n0 == 0), doB = (m0 == 0);

        for (int t = 0; t < 8; ++t) {
            const float* ga = Ab + (size_t)(m0 + prow) * N_ + kbeg + t * 64 + cs * 4;
            const float* gb = Bb + (size_t)(n0 + prow) * N_ + kbeg + t * 64 + cs * 4;
#pragma unroll
            for (int p = 0; p < 8; ++p)
                __builtin_amdgcn_global_load_lds(
                    (const __attribute__((address_space(1))) void*)(ga + (size_t)p * 16 * N_),
                    (__attribute__((address_space(3))) void*)((char*)AsF + ldso + p * 4096),
                    16, 0, 0);
#pragma unroll
            for (int p = 0; p < 8; ++p)
                __builtin_amdgcn_global_load_lds(
                    (const __attribute__((address_space(1))) void*)(gb + (size_t)p * 16 * N_),
                    (__attribute__((address_space(3))) void*)((char*)BsF + ldso + p * 4096),
                    16, 0, 0);
            __syncthreads();

#pragma unroll
            for (int kk = 0; kk < 64; kk += 32) {
                bf16x8 af[4], bfr[4];
                const int kcol = kk + (lane >> 4) * 8;
                const int c1 = kcol >> 2;
#pragma unroll
                for (int m = 0; m < 4; ++m) {
                    const int r = wr * 64 + (lane & 15) + m * 16;
                    f32x4 lo = *(const f32x4*)((const char*)AsF + r * 256 + ((c1 ^ (r & 7)) << 4));
                    f32x4 hi = *(const f32x4*)((const char*)AsF + r * 256 + (((c1 + 1) ^ (r & 7)) << 4));
                    bf16x8 fr;
                    fr[0] = (bf16_t)lo[0]; fr[1] = (bf16_t)lo[1];
                    fr[2] = (bf16_t)lo[2]; fr[3] = (bf16_t)lo[3];
                    fr[4] = (bf16_t)hi[0]; fr[5] = (bf16_t)hi[1];
                    fr[6] = (bf16_t)hi[2]; fr[7] = (bf16_t)hi[3];
                    af[m] = fr;
                }
#pragma unroll
                for (int n = 0; n < 4; ++n) {
                    const int r = wc * 64 + (lane & 15) + n * 16;
                    f32x4 lo = *(const f32x4*)((const char*)BsF + r * 256 + ((c1 ^ (r & 7)) << 4));
                    f32x4 hi = *(const f32x4*)((const char*)BsF + r * 256 + (((c1 + 1) ^ (r & 7)) << 4));
                    bf16x8 fr;
                    fr[0] = (bf16_t)lo[0]; fr[1] = (bf16_t)lo[1];
                    fr[2] = (bf16_t)lo[2]; fr[3] = (bf16_t)lo[3];
                    fr[4] = (bf16_t)hi[0]; fr[5] = (bf16_t)hi[1];
                    fr[6] = (bf16_t)hi[2]; fr[7] = (bf16_t)hi[3];
                    bfr[n] = fr;
                }
#pragma unroll
                for (int m = 0; m < 4; ++m)
#pragma unroll
                    for (int n = 0; n < 4; ++n)
                        acc[m][n] = __builtin_amdgcn_mfma_f32_16x16x32_bf16(
                            af[m], bfr[n], acc[m][n], 0, 0, 0);
            }

            if (doA) {
#pragma unroll
                for (int u = 0; u < 8; ++u) {
                    const int slot = ((hh * 8 + u) + srr) & 15;
                    f32x4 vv = *(const f32x4*)((const char*)AsF + srr * 256 + slot * 16);
                    hsA += vv[0] + vv[1] + vv[2] + vv[3];
                }
            }
            if (doB) {
#pragma unroll
                for (int u = 0; u < 8; ++u) {
                    const int slot = ((hh * 8 + u) + srr) & 15;
                    f32x4 vv = *(const f32x4*)((const char*)BsF + srr * 256 + slot * 16);
                    hsB += vv[0] + vv[1] + vv[2] + vv[3];
                }
            }
            __syncthreads();
        }

        const int rj = (lane >> 4) * 4;
        const int cc = lane & 15;
        const int z = bz * 4 + sp;
#pragma unroll
        for (int m = 0; m < 4; ++m)
#pragma unroll
            for (int n = 0; n < 4; ++n) {
                const int col = n0 + wc * 64 + n * 16 + cc;
                f32x4 vv = acc[m][n];
#pragma unroll
                for (int j = 0; j < 4; ++j) {
                    const int row = m0 + wr * 64 + m * 16 + rj + j;
                    Dp[(size_t)z * sCC + (size_t)row * C_ + col] = (bf16_t)vv[j];
                }
            }
        if (doA) {
            hsA += __shfl_xor(hsA, 1, 64);
            if (!hh) sk4[(size_t)(sp * B_ + bz) * C_ + m0 + srr] = hsA;
        }
        if (doB) {
            hsB += __shfl_xor(hsB, 1, 64);
            if (!hh) sv4[(size_t)(sp * B_ + bz) * C_ + n0 + srr] = hsB;
        }
    } else if (f < 576) {
        // ---- M = WqT.WkT^T (64-tile bf16; LDS aliased onto AsF/BsF) ----
        bf16_t* As = (bf16_t*)AsF;
        bf16_t* Bs = (bf16_t*)BsF;
        const int g = f - 512;
        const int m0 = (g >> 3) * 64, n0 = (g & 7) * 64;
        f32x4 acc[2][2];
#pragma unroll
        for (int i = 0; i < 2; ++i)
#pragma unroll
            for (int j = 0; j < 2; ++j) acc[i][j] = 0.f;
        const int srow = tid >> 3;
        const int scol = ((tid & 7) ^ (srow & 7)) * 8;
        const int ldso = tid * 16;
        for (int t = 0; t < 8; ++t) {
            const bf16_t* ga = WqT + (size_t)(m0 + srow) * C_ + t * 64 + scol;
            const bf16_t* gb = WkT + (size_t)(n0 + srow) * C_ + t * 64 + scol;
#pragma unroll
            for (int p = 0; p < 2; ++p)
                __builtin_amdgcn_global_load_lds(
                    (const __attribute__((address_space(1))) void*)(ga + (size_t)p * 32 * C_),
                    (__attribute__((address_space(3))) void*)((char*)As + ldso + p * 4096),
                    16, 0, 0);
#pragma unroll
            for (int p = 0; p < 2; ++p)
                __builtin_amdgcn_global_load_lds(
                    (const __attribute__((address_space(1))) void*)(gb + (size_t)p * 32 * C_),
                    (__attribute__((address_space(3))) void*)((char*)Bs + ldso + p * 4096),
                    16, 0, 0);
            __syncthreads();
#pragma unroll
            for (int kk = 0; kk < 64; kk += 32) {
                bf16x8 af[2], bfr[2];
                const int kcol = kk + (lane >> 4) * 8;
                const int kcn = kcol >> 3;
#pragma unroll
                for (int m = 0; m < 2; ++m) {
                    const int r = wr * 32 + (lane & 15) + m * 16;
                    af[m] = *(const bf16x8*)((const char*)As + r * 128 +
                                             ((kcn ^ (r & 7)) << 4));
                }
#pragma unroll
                for (int n = 0; n < 2; ++n) {
                    const int r = wc * 32 + (lane & 15) + n * 16;
                    bfr[n] = *(const bf16x8*)((const char*)Bs + r * 128 +
                                              ((kcn ^ (r & 7)) << 4));
                }
#pragma unroll
                for (int m = 0; m < 2; ++m)
#pragma unroll
                    for (int n = 0; n < 2; ++n)
                        acc[m][n] = __builtin_amdgcn_mfma_f32_16x16x32_bf16(
                            af[m], bfr[n], acc[m][n], 0, 0, 0);
            }
            __syncthreads();
        }
        const int rj = (lane >> 4) * 4;
        const int cc = lane & 15;
#pragma unroll
        for (int m = 0; m < 2; ++m)
#pragma unroll
            for (int n = 0; n < 2; ++n) {
                const int col = n0 + wc * 32 + n * 16 + cc;
                f32x4 vv = acc[m][n];
#pragma unroll
                for (int j = 0; j < 4; ++j) {
                    const int row = m0 + wr * 32 + m * 16 + rj + j;
                    M[(size_t)row * C_ + col] = (bf16_t)vv[j];
                }
            }
    } else {
        const int j = f - 576;
        const bf16_t* W = (j < 8) ? WkT : WqT;
        const float* bb = (j < 8) ? bq : bk;
        float* out = (j < 8) ? gk : va;
        const int row = (j & 7) * 64 + (tid >> 2);
        const int c0 = (tid & 3) * 128;
        const bf16_t* rp = W + (size_t)row * C_ + c0;
        float acc = 0.f;
#pragma unroll
        for (int e = 0; e < 128; e += 8) {
            bf16x8 vv = *(const bf16x8*)(rp + e);
#pragma unroll
            for (int x = 0; x < 8; ++x) acc += (float)vv[x] * bb[c0 + e + x];
        }
        acc += __shfl_xor(acc, 1, 64);
        acc += __shfl_xor(acc, 2, 64);
        if ((tid & 3) == 0) out[row] = acc;
    }
}

// ---------------------------------------------------------------------------
// p1_fused (528 blocks):
//   0..511   P1[bz][c2,i] = sum_{sp,j} Wv[c2,j] * Dp[bz*4+sp][i,j]
//            (64-tile, K=2048 over 4 Dp slices; fp32 accumulate)
//   512..519 u[b] = Wv . (sum_sp sv4[b])
//   520..527 vbraw[b] = M . (sum_sp sk4[b]);  s2[b] = sk.gk + N*s1
// ---------------------------------------------------------------------------
__global__ __launch_bounds__(256) void p1_fused_kernel(
    const bf16_t* __restrict__ Wvb, const bf16_t* __restrict__ Dp,
    bf16_t* __restrict__ P1, const bf16_t* __restrict__ M,
    const float* __restrict__ sk4, const float* __restrict__ sv4,
    const float* __restrict__ gk, const float* __restrict__ s1p,
    float* __restrict__ u, float* __restrict__ vbraw, float* __restrict__ s2)
{
    __shared__ __align__(16) bf16_t As[64 * 64];
    __shared__ __align__(16) bf16_t Bs[64 * 64];
    __shared__ float svec[C_];
    __shared__ float red[256];
    const int f = blockIdx.x;
    const int tid = threadIdx.x, lane = tid & 63, wave = tid >> 6;
    const int wr = wave >> 1, wc = wave & 1;
    const size_t sCC = (size_t)C_ * C_;
    const size_t st = (size_t)B_ * C_;

    if (f < 512) {
        const int bz = f >> 6;
        const int m0 = ((f >> 3) & 7) * 64, n0 = (f & 7) * 64;
        f32x4 acc[2][2];
#pragma unroll
        for (int i = 0; i < 2; ++i)
#pragma unroll
            for (int j = 0; j < 2; ++j) acc[i][j] = 0.f;
        const int srow = tid >> 3;
        const int scol = ((tid & 7) ^ (srow & 7)) * 8;
        const int ldso = tid * 16;

        for (int sp = 0; sp < 4; ++sp) {
            const bf16_t* Bb = Dp + (size_t)(bz * 4 + sp) * sCC;
            for (int t = 0; t < 8; ++t) {
                const bf16_t* ga = Wvb + (size_t)(m0 + srow) * C_ + t * 64 + scol;
                const bf16_t* gb = Bb + (size_t)(n0 + srow) * C_ + t * 64 + scol;
#pragma unroll
                for (int p = 0; p < 2; ++p)
                    __builtin_amdgcn_global_load_lds(
                        (const __attribute__((address_space(1))) void*)(ga + (size_t)p * 32 * C_),
                        (__attribute__((address_space(3))) void*)((char*)As + ldso + p * 4096),
                        16, 0, 0);
#pragma unroll
                for (int p = 0; p < 2; ++p)
                    __builtin_amdgcn_global_load_lds(
                        (const __attribute__((address_space(1))) void*)(gb + (size_t)p * 32 * C_),
                        (__attribute__((address_space(3))) void*)((char*)Bs + ldso + p * 4096),
                        16, 0, 0);
                __syncthreads();
#pragma unroll
                for (int kk = 0; kk < 64; kk += 32) {
                    bf16x8 af[2], bfr[2];
                    const int kcol = kk + (lane >> 4) * 8;
                    const int kcn = kcol >> 3;
#pragma unroll
                    for (int m = 0; m < 2; ++m) {
                        const int r = wr * 32 + (lane & 15) + m * 16;
                        af[m] = *(const bf16x8*)((const char*)As + r * 128 +
                                                 ((kcn ^ (r & 7)) << 4));
                    }
#pragma unroll
                    for (int n = 0; n < 2; ++n) {
                        const int r = wc * 32 + (lane & 15) + n * 16;
                        bfr[n] = *(const bf16x8*)((const char*)Bs + r * 128 +
                                                  ((kcn ^ (r & 7)) << 4));
                    }
#pragma unroll
                    for (int m = 0; m < 2; ++m)
#pragma unroll
                        for (int n = 0; n < 2; ++n)
                            acc[m][n] = __builtin_amdgcn_mfma_f32_16x16x32_bf16(
                                af[m], bfr[n], acc[m][n], 0, 0, 0);
                }
                __syncthreads();
            }
        }
        const int rj = (lane >> 4) * 4;
        const int cc = lane & 15;
#pragma unroll
        for (int m = 0; m < 2; ++m)
#pragma unroll
            for (int n = 0; n < 2; ++n) {
                const int col = n0 + wc * 32 + n * 16 + cc;
                f32x4 vv = acc[m][n];
#pragma unroll
                for (int j = 0; j < 4; ++j) {
                    const int row = m0 + wr * 32 + m * 16 + rj + j;
                    P1[(size_t)bz * sCC + (size_t)row * C_ + col] = (bf16_t)vv[j];
                }
            }
    } else if (f < 520) {
        const int b = f - 512;
        const float* s4 = sv4 + (size_t)b * C_;
#pragma unroll
        for (int rr = 0; rr < 2; ++rr) {
            const int j = tid * 2 + rr;
            svec[j] = s4[j] + s4[st + j] + s4[2 * st + j] + s4[3 * st + j];
        }
        __syncthreads();
        const int c = tid * 2;
#pragma unroll
        for (int rr = 0; rr < 2; ++rr) {
            const bf16_t* row = Wvb + (size_t)(c + rr) * C_;
            float acc = 0.f;
            for (int j = 0; j < C_; j += 8) {
                bf16x8 vv = *(const bf16x8*)(row + j);
#pragma unroll
                for (int e = 0; e < 8; ++e) acc += (float)vv[e] * svec[j + e];
            }
            u[b * C_ + c + rr] = acc;
        }
    } else {
        const int b = f - 520;
        const float* s4 = sk4 + (size_t)b * C_;
#pragma unroll
        for (int rr = 0; rr < 2; ++rr) {
            const int j = tid * 2 + rr;
            svec[j] = s4[j] + s4[st + j] + s4[2 * st + j] + s4[3 * st + j];
        }
        __syncthreads();
        const int c = tid * 2;
#pragma unroll
        for (int rr = 0; rr < 2; ++rr) {
            const bf16_t* row = M + (size_t)(c + rr) * C_;
            float acc = 0.f;
            for (int j = 0; j < C_; j += 8) {
                bf16x8 vv = *(const bf16x8*)(row + j);
#pragma unroll
                for (int e = 0; e < 8; ++e) acc += (float)vv[e] * svec[j + e];
            }
            vbraw[b * C_ + c + rr] = acc;
        }
        float p = svec[tid] * gk[tid] + svec[tid + 256] * gk[tid + 256];
        red[tid] = p;
        __syncthreads();
        for (int s = 128; s > 0; s >>= 1) {
            if (tid < s) red[tid] += red[tid + s];
            __syncthreads();
        }
        if (tid == 0) s2[b] = red[0] + 2048.0f * s1p[0];
    }
}

// ---------------------------------------------------------------------------
// HT GEMM (64-tile, K=512): HT = P1.M^T + u (x) va + bv (x) (vbraw + N*va);
// x==0 blocks also compute h (r11-verified fold).
// ---------------------------------------------------------------------------
__global__ __launch_bounds__(256) void gemm_ht(
    const bf16_t* __restrict__ A, const bf16_t* __restrict__ Bm,
    bf16_t* __restrict__ Cout,
    const float* __restrict__ e0, const float* __restrict__ e1,
    const float* __restrict__ e2, const float* __restrict__ e3,
    const float* __restrict__ bqv, float* __restrict__ hout,
    const float* __restrict__ s1p, const float* __restrict__ s2p)
{
    __shared__ __align__(16) bf16_t As[64 * 64];
    __shared__ __align__(16) bf16_t Bs[64 * 64];

    const int tid = threadIdx.x, lane = tid & 63, wave = tid >> 6;
    const int wr = wave >> 1, wc = wave & 1;
    const int bz = blockIdx.z;
    const int m0 = blockIdx.y * 64, n0 = blockIdx.x * 64;
    const size_t sCC = (size_t)C_ * C_;

    const bf16_t* Ab = A + (size_t)bz * sCC;

    f32x4 acc[2][2];
#pragma unroll
    for (int i = 0; i < 2; ++i)
#pragma unroll
        for (int j = 0; j < 2; ++j) acc[i][j] = 0.f;

    const int srow = tid >> 3;
    const int scol = ((tid & 7) ^ (srow & 7)) * 8;
    const int ldso = tid * 16;

    float hacc = 0.f;
    const bool doH = (blockIdx.x == 0);

    for (int t = 0; t < 8; ++t) {
        const bf16_t* ga = Ab + (size_t)(m0 + srow) * C_ + t * 64 + scol;
        const bf16_t* gb = Bm + (size_t)(n0 + srow) * C_ + t * 64 + scol;
#pragma unroll
        for (int p = 0; p < 2; ++p)
            __builtin_amdgcn_global_load_lds(
                (const __attribute__((address_space(1))) void*)(ga + (size_t)p * 32 * C_),
                (__attribute__((address_space(3))) void*)((char*)As + ldso + p * 4096),
                16, 0, 0);
#pragma unroll
        for (int p = 0; p < 2; ++p)
            __builtin_amdgcn_global_load_lds(
                (const __attribute__((address_space(1))) void*)(gb + (size_t)p * 32 * C_),
                (__attribute__((address_space(3))) void*)((char*)Bs + ldso + p * 4096),
                16, 0, 0);
        __syncthreads();

#pragma unroll
        for (int kk = 0; kk < 64; kk += 32) {
            bf16x8 af[2], bfr[2];
            const int kcol = kk + (lane >> 4) * 8;
            const int kcn = kcol >> 3;
#pragma unroll
            for (int m = 0; m < 2; ++m) {
                const int r = wr * 32 + (lane & 15) + m * 16;
                af[m] = *(const bf16x8*)((const char*)As + r * 128 +
                                         ((kcn ^ (r & 7)) << 4));
            }
#pragma unroll
            for (int n = 0; n < 2; ++n) {
                const int r = wc * 32 + (lane & 15) + n * 16;
                bfr[n] = *(const bf16x8*)((const char*)Bs + r * 128 +
                                          ((kcn ^ (r & 7)) << 4));
            }
#pragma unroll
            for (int m = 0; m < 2; ++m)
#pragma unroll
                for (int n = 0; n < 2; ++n)
                    acc[m][n] = __builtin_amdgcn_mfma_f32_16x16x32_bf16(
                        af[m], bfr[n], acc[m][n], 0, 0, 0);
        }
        if (doH) {
            const int rr = tid >> 2, qq = tid & 3;
#pragma unroll
            for (int uq = 0; uq < 2; ++uq) {
                const int c = qq * 2 + uq;
                bf16x8 av = *(const bf16x8*)((const char*)As + rr * 128 +
                                             ((c ^ (rr & 7)) << 4));
                const float* bp = bqv + t * 64 + c * 8;
#pragma unroll
                for (int e = 0; e < 8; ++e) hacc += (float)av[e] * bp[e];
            }
        }
        __syncthreads();
    }

    const int rj = (lane >> 4) * 4;
    const int cc = lane & 15;
#pragma unroll
    for (int m = 0; m < 2; ++m) {
#pragma unroll
        for (int n = 0; n < 2; ++n) {
            const int col = n0 + wc * 32 + n * 16 + cc;
            f32x4 vv = acc[m][n];
#pragma unroll
            for (int j = 0; j < 4; ++j) {
                const int row = m0 + wr * 32 + m * 16 + rj + j;
                float val = vv[j] + e0[bz * C_ + row] * e1[col] +
                            e2[row] * (e3[bz * C_ + col] + 2048.0f * e1[col]);
                Cout[(size_t)bz * sCC + (size_t)row * C_ + col] = (bf16_t)val;
            }
        }
    }
    if (doH) {
        hacc += __shfl_xor(hacc, 1, 64);
        hacc += __shfl_xor(hacc, 2, 64);
        if ((tid & 3) == 0) {
            const int row = m0 + (tid >> 2);
            hout[bz * C_ + row] = hacc + e0[bz * C_ + row] * s1p[0] +
                                  e2[row] * s2p[bz];
        }
    }
}

// ---------------------------------------------------------------------------
// Final GEMM: out[c,n] = sum_i HT[c,i]*qT[n,i] + h[b][c] + q[c,n] (fp32 resid).
// 1-D XCD-swizzled grid (512).
// ---------------------------------------------------------------------------
__global__ __launch_bounds__(256) void gemm_final(
    const bf16_t* __restrict__ A, const bf16_t* __restrict__ Bm,
    float* __restrict__ Cout, const float* __restrict__ qres,
    const float* __restrict__ hvec)
{
    __shared__ __align__(16) bf16_t As[128 * 64];
    __shared__ __align__(16) bf16_t Bs[128 * 64];

    const int f = blockIdx.x;
    const int xcd = f & 7, sl = f >> 3;
    const int g = xcd + 8 * (sl >> 2);
    const int m0 = (sl & 3) * 128;
    const int bz = g >> 4;
    const int n0 = (g & 15) * 128;
    const int K = C_;

    const int tid = threadIdx.x, lane = tid & 63, wave = tid >> 6;
    const int wr = wave >> 1, wc = wave & 1;

    const bf16_t* Ab = A + (size_t)bz * ((size_t)C_ * C_);
    const bf16_t* Bb = Bm + (size_t)bz * ((size_t)N_ * C_);

    f32x4 acc[4][4];
#pragma unroll
    for (int i = 0; i < 4; ++i)
#pragma unroll
        for (int j = 0; j < 4; ++j) acc[i][j] = 0.f;

    const int srow = tid >> 3;
    const int scol = ((tid & 7) ^ (srow & 7)) * 8;
    const int ldso = tid * 16;

    for (int t = 0; t < 8; ++t) {
        const bf16_t* ga = Ab + (size_t)(m0 + srow) * K + t * 64 + scol;
        const bf16_t* gb = Bb + (size_t)(n0 + srow) * K + t * 64 + scol;
#pragma unroll
        for (int p = 0; p < 4; ++p)
            __builtin_amdgcn_global_load_lds(
                (const __attribute__((address_space(1))) void*)(ga + (size_t)p * 32 * K),
                (__attribute__((address_space(3))) void*)((char*)As + ldso + p * 4096),
                16, 0, 0);
#pragma unroll
        for (int p = 0; p < 4; ++p)
            __builtin_amdgcn_global_load_lds(
                (const __attribute__((address_space(1))) void*)(gb + (size_t)p * 32 * K),
                (__attribute__((address_space(3))) void*)((char*)Bs + ldso + p * 4096),
                16, 0, 0);
        __syncthreads();

#pragma unroll
        for (int kk = 0; kk < 64; kk += 32) {
            bf16x8 af[4], bfr[4];
            const int kcol = kk + (lane >> 4) * 8;
            const int kcn = kcol >> 3;
#pragma unroll
            for (int m = 0; m < 4; ++m) {
                const int r = wr * 64 + (lane & 15) + m * 16;
                af[m] = *(const bf16x8*)((const char*)As + r * 128 +
                                         ((kcn ^ (r & 7)) << 4));
            }
#pragma unroll
            for (int n = 0; n < 4; ++n) {
                const int r = wc * 64 + (lane & 15) + n * 16;
                bfr[n] = *(const bf16x8*)((const char*)Bs + r * 128 +
                                          ((kcn ^ (r & 7)) << 4));
            }
#pragma unroll
            for (int m = 0; m < 4; ++m)
#pragma unroll
                for (int n = 0; n < 4; ++n)
                    acc[m][n] = __builtin_amdgcn_mfma_f32_16x16x32_bf16(
                        af[m], bfr[n], acc[m][n], 0, 0, 0);
        }
        __syncthreads();
    }

    const int rj = (lane >> 4) * 4;
    const int cc = lane & 15;
    const size_t ob = (size_t)bz * ((size_t)C_ * N_);
#pragma unroll
    for (int m = 0; m < 4; ++m) {
#pragma unroll
        for (int n = 0; n < 4; ++n) {
            const int col = n0 + wc * 64 + n * 16 + cc;
            f32x4 vv = acc[m][n];
#pragma unroll
            for (int j = 0; j < 4; ++j) {
                const int row = m0 + wr * 64 + m * 16 + rj + j;
                const size_t o = ob + (size_t)row * N_ + col;
                Cout[o] = vv[j] + hvec[bz * C_ + row] + qres[o];
            }
        }
    }
}

// ---------------------------------------------------------------------------
extern "C" void kernel_launch(void* const* d_in, const int* in_sizes, int n_in,
                              void* d_out, int out_size, void* d_ws, size_t ws_size,
                              hipStream_t stream)
{
    (void)in_sizes; (void)n_in; (void)out_size; (void)ws_size;
    const float* q  = (const float*)d_in[0];
    const float* k  = (const float*)d_in[1];
    const float* v  = (const float*)d_in[2];
    const float* wq = (const float*)d_in[3];
    const float* bq = (const float*)d_in[4];
    const float* wk = (const float*)d_in[5];
    const float* bk = (const float*)d_in[6];
    const float* wv = (const float*)d_in[7];
    const float* bv = (const float*)d_in[8];
    float* out = (float*)d_out;

    char* ws = (char*)d_ws;
    const size_t WSZ = (size_t)C_ * C_ * 2;            // 512 KB
    const size_t TSZ = (size_t)B_ * N_ * C_ * 2;       // 16.78 MB
    const size_t SCZ = (size_t)B_ * C_ * C_ * 2;       // 4.19 MB
    const size_t VSZ = (size_t)B_ * C_ * 4;            // 16 KB
    size_t off = 0;
    bf16_t* WqTb = (bf16_t*)(ws + off); off += WSZ;
    bf16_t* WkTb = (bf16_t*)(ws + off); off += WSZ;
    bf16_t* Wvb  = (bf16_t*)(ws + off); off += WSZ;
    bf16_t* M    = (bf16_t*)(ws + off); off += WSZ;
    bf16_t* qT   = (bf16_t*)(ws + off); off += TSZ;
    bf16_t* Dp   = (bf16_t*)(ws + off); off += TSZ;    // 32 x sCC split partials
    bf16_t* P1   = (bf16_t*)(ws + off); off += SCZ;
    bf16_t* HT   = (bf16_t*)(ws + off); off += SCZ;
    float*  sk4  = (float*)(ws + off);  off += 4 * VSZ;
    float*  sv4  = (float*)(ws + off);  off += 4 * VSZ;
    float*  gk   = (float*)(ws + off);  off += C_ * 4;
    float*  va   = (float*)(ws + off);  off += C_ * 4;
    float*  s1p  = (float*)(ws + off);  off += 64;
    float*  s2   = (float*)(ws + off);  off += 64;
    float*  uu   = (float*)(ws + off);  off += VSZ;
    float*  vbr  = (float*)(ws + off);  off += VSZ;
    float*  hb   = (float*)(ws + off);  off += VSZ;

    const dim3 blk(256);

    // 1. prep: q->qT + weights (WqT/WkT/Wv/s1). No k/v cast pass.
    prep_qw_kernel<<<dim3(2241), blk, 0, stream>>>(
        q, wq, wk, wv, bq, bk, qT, WqTb, WkTb, Wvb, s1p);

    // 2. D partials from fp32 k,v directly (r9 body) + M + gk/va
    dkv_M_kernel<<<dim3(592), blk, 0, stream>>>(
        k, v, Dp, sk4, sv4, WqTb, WkTb, M, bq, bk, gk, va);

    // 3. P1 = Wv . (sum_sp Dp)^T (K=2048, reduce fused) + u/vbraw/s2
    p1_fused_kernel<<<dim3(528), blk, 0, stream>>>(
        Wvb, Dp, P1, M, sk4, sv4, gk, s1p, uu, vbr, s2);

    // 4. HT = P1.M^T + rank-1; h folded into x==0 blocks
    gemm_ht<<<dim3(8, 8, B_), blk, 0, stream>>>(
        P1, M, HT, uu, va, bv, vbr, gk, hb, s1p, s2);

    // 5. out = HT.qT^T + h + q  (fp32 residual read directly)
    gemm_final<<<dim3(512), blk, 0, stream>>>(HT, qT, out, q, hb);
}